// Round 7
// baseline (92.693 us; speedup 1.0000x reference)
//
#include <hip/hip_runtime.h>

#define N_IN   4096
#define N_OUT  4082      // 4096 - 15 + 1
#define KS     15
#define TM     128       // output rows per block (4 chunks x 32)
#define TN     256       // output cols per block
#define CH     32        // output rows per chunk
#define NCH    4         // chunks per block
#define PR     142       // patch rows needed (TM + KS - 1)
#define PC     272       // patch cols staged (TN + 16)
#define C4R    68        // float4 chunks per patch row (PC/4)
#define RING   128       // ring rows: span per chunk = 78 < 128 -> no clobber
#define PITEMS (46 * C4R)          // prologue items (rows [0,46)) = 3128
#define CITEMS (CH * C4R)          // per-chunk staging items = 2176

// LDS: 128-row ring, 128*272*2B = 69,632 B -> 2 blocks/CU at 512 thr.
// Bank note: pitch 272 bf16 = 136 words == 8 mod 32 -> conflict-free b128 floor
// (R6 measured 0 conflicts). Linear, no swizzle.
// ILP note: 4 independent acc chains per wave (2 row-bands x 2 col-tiles).

typedef __attribute__((ext_vector_type(8))) short bf16x8;
typedef __attribute__((ext_vector_type(4))) float f32x4;

__device__ inline unsigned short f2bf(float f) {   // round-to-nearest-even
    unsigned u = __builtin_bit_cast(unsigned, f);
    u += 0x7FFFu + ((u >> 16) & 1u);
    return (unsigned short)(u >> 16);
}
__device__ inline ushort4 f2bf4(float4 v) {
    ushort4 b; b.x = f2bf(v.x); b.y = f2bf(v.y); b.z = f2bf(v.z); b.w = f2bf(v.w);
    return b;
}

// load one staging item (patch row = base + it/C4R) into v, zero-padded
#define ISSUE_ITEM(base, it, v) {                                         \
    const int _row = (base) + (it) / C4R;                                 \
    const int _c4  = (it) % C4R;                                          \
    const int _gr  = r0 + _row;                                           \
    const int _gc  = c0 + _c4 * 4;                                        \
    if (_row < PR && _gr < N_IN && _gc < N_IN)                            \
        v = *reinterpret_cast<const float4*>(&x[_gr * N_IN + _gc]);       \
}
// convert + write item into its ring slot
#define COMMIT_ITEM(base, it, v) {                                        \
    const int _row = (base) + (it) / C4R;                                 \
    if (_row < PR) {                                                      \
        const int _ring = _row & (RING - 1);                              \
        const int _c4   = (it) % C4R;                                     \
        *reinterpret_cast<ushort4*>(&xs[_ring * PC + _c4 * 4]) = f2bf4(v);\
    }                                                                     \
}

__global__ __launch_bounds__(512, 4) void Conv2DScratch_82025285419642_kernel(
    const float* __restrict__ x, const float* __restrict__ w,
    const float* __restrict__ bias, float* __restrict__ out)
{
    __shared__ unsigned short xs[RING * PC];   // 69,632 B

    const int tid  = threadIdx.x;
    const int lane = tid & 63;
    const int wv   = tid >> 6;            // 0..7 : wave owns cols [32wv, 32wv+32)
    const int m    = lane & 15;           // A row within band / D col
    const int g    = lane >> 4;           // k-group / D row group

    // bijective XCD-chunked block swizzle (512 blocks, 8 XCDs, 64 each)
    const int bid = blockIdx.x;
    const int s   = ((bid & 7) << 6) | (bid >> 3);
    const int c0  = (s & 15) * TN;        // output col base
    const int r0  = (s >> 4) * TM;        // output row base

    // ---- prologue: stage patch rows [0,46); build B frags while in flight ----
    float4 p0 = make_float4(0.f,0.f,0.f,0.f), p1 = p0, p2 = p0, p3 = p0,
           p4 = p0, p5 = p0, p6 = p0;
    ISSUE_ITEM(0, tid,        p0);
    ISSUE_ITEM(0, tid +  512, p1);
    ISSUE_ITEM(0, tid + 1024, p2);
    ISSUE_ITEM(0, tid + 1536, p3);
    ISSUE_ITEM(0, tid + 2048, p4);
    ISSUE_ITEM(0, tid + 2560, p5);
    if (tid + 3072 < PITEMS) ISSUE_ITEM(0, tid + 3072, p6);

    // B[(p,q)][n] = w[p][q-n]; lane: n = m, q = g*8+e  (verified R2)
    bf16x8 bfrag[KS];
    #pragma unroll
    for (int p = 0; p < KS; ++p) {
        #pragma unroll
        for (int e = 0; e < 8; ++e) {
            const int idx = g * 8 + e - m;               // filter col
            const float vv = (idx >= 0 && idx < KS) ? w[p * KS + idx] : 0.f;
            bfrag[p][e] = (short)f2bf(vv);
        }
    }
    const float b0 = bias[0];

    COMMIT_ITEM(0, tid,        p0);
    COMMIT_ITEM(0, tid +  512, p1);
    COMMIT_ITEM(0, tid + 1024, p2);
    COMMIT_ITEM(0, tid + 1536, p3);
    COMMIT_ITEM(0, tid + 2048, p4);
    COMMIT_ITEM(0, tid + 2560, p5);
    if (tid + 3072 < PITEMS) COMMIT_ITEM(0, tid + 3072, p6);
    __syncthreads();

    const int colbase = wv * 32 + g * 8;   // A-frag col (bf16) within ring row

    // ---- ring loop: compute out rows [32c,32c+32), stage patch [32c+46,32c+78) ----
    for (int c = 0; c < NCH; ++c) {
        const int srow = 46 + c * CH;      // staging base row this chunk

        float4 s0 = make_float4(0.f,0.f,0.f,0.f), s1 = s0, s2 = s0;
        ISSUE_ITEM(srow, tid,        s0);
        ISSUE_ITEM(srow, tid +  512, s1);
        ISSUE_ITEM(srow, tid + 1024, s2);

        // row-band 0 (out rows 32c .. 32c+16)
        f32x4 acc00 = {0.f,0.f,0.f,0.f}, acc01 = acc00;
        {
            const int rb = c * CH + m;
            #pragma unroll
            for (int p = 0; p < KS; ++p) {
                const unsigned short* ap = &xs[((rb + p) & (RING - 1)) * PC + colbase];
                acc00 = __builtin_amdgcn_mfma_f32_16x16x32_bf16(
                    *reinterpret_cast<const bf16x8*>(ap +  0), bfrag[p], acc00, 0, 0, 0);
                acc01 = __builtin_amdgcn_mfma_f32_16x16x32_bf16(
                    *reinterpret_cast<const bf16x8*>(ap + 16), bfrag[p], acc01, 0, 0, 0);
            }
        }
        COMMIT_ITEM(srow, tid,        s0);
        COMMIT_ITEM(srow, tid +  512, s1);
        COMMIT_ITEM(srow, tid + 1024, s2);

        float4 s3 = make_float4(0.f,0.f,0.f,0.f), s4 = s3;
        ISSUE_ITEM(srow, tid + 1536, s3);
        if (tid + 2048 < CITEMS) ISSUE_ITEM(srow, tid + 2048, s4);

        // row-band 1 (out rows 32c+16 .. 32c+32)
        f32x4 acc10 = {0.f,0.f,0.f,0.f}, acc11 = acc10;
        {
            const int rb = c * CH + 16 + m;
            #pragma unroll
            for (int p = 0; p < KS; ++p) {
                const unsigned short* ap = &xs[((rb + p) & (RING - 1)) * PC + colbase];
                acc10 = __builtin_amdgcn_mfma_f32_16x16x32_bf16(
                    *reinterpret_cast<const bf16x8*>(ap +  0), bfrag[p], acc10, 0, 0, 0);
                acc11 = __builtin_amdgcn_mfma_f32_16x16x32_bf16(
                    *reinterpret_cast<const bf16x8*>(ap + 16), bfrag[p], acc11, 0, 0, 0);
            }
        }
        COMMIT_ITEM(srow, tid + 1536, s3);
        if (tid + 2048 < CITEMS) COMMIT_ITEM(srow, tid + 2048, s4);

        // stores (nontemporal: output never re-read; keep L2 for input)
        const int ocol = c0 + wv * 32 + m;
        #define STORE_TILE(tr, tc, a) {                                   \
            const int _oc = ocol + (tc) * 16;                             \
            if (_oc < N_OUT) {                                            \
                const int _or0 = r0 + c * CH + (tr) * 16 + g * 4;         \
                _Pragma("unroll")                                         \
                for (int r = 0; r < 4; ++r) {                             \
                    if (_or0 + r < N_OUT)                                 \
                        __builtin_nontemporal_store(a[r] + b0,            \
                            &out[(_or0 + r) * N_OUT + _oc]);              \
                }                                                         \
            }                                                             \
        }
        STORE_TILE(0, 0, acc00); STORE_TILE(0, 1, acc01);
        STORE_TILE(1, 0, acc10); STORE_TILE(1, 1, acc11);
        #undef STORE_TILE

        __syncthreads();                   // staged rows visible for chunk c+1
    }
}

extern "C" void kernel_launch(void* const* d_in, const int* in_sizes, int n_in,
                              void* d_out, int out_size, void* d_ws, size_t ws_size,
                              hipStream_t stream) {
    const float* x    = (const float*)d_in[0];
    const float* w    = (const float*)d_in[1];
    const float* bias = (const float*)d_in[2];
    float* out        = (float*)d_out;

    dim3 block(512);
    dim3 grid(16 * 32);   // 512 blocks, swizzled in-kernel; 2/CU, all resident
    Conv2DScratch_82025285419642_kernel<<<grid, block, 0, stream>>>(x, w, bias, out);
}

// Round 8
// 58.063 us; speedup vs baseline: 1.5964x; 1.5964x over previous
//
#include <hip/hip_runtime.h>

#define N_IN   4096
#define N_OUT  4082      // 4096 - 15 + 1
#define KS     15
#define TM     128       // output rows per block (4 chunks x 32)
#define TN     256       // output cols per block
#define CH     32        // output rows per chunk (2 bands x 16, sequential)
#define NCH    4         // chunks per block
#define PR     142       // patch rows needed (TM + KS - 1)
#define PC     272       // patch cols staged (TN + 16)
#define C4R    68        // float4 chunks per patch row (PC/4)
#define RING   128       // ring rows: per-chunk span 78 < 128 -> no clobber
#define PITEMS (46 * C4R)          // prologue items (rows [0,46)) = 3128
#define CITEMS (CH * C4R)          // per-chunk staging items = 2176

// LDS: 128-row ring, 128*272*2B = 69,632 B -> 2 blocks/CU at 512 thr.
// Bank: pitch 272 bf16 = 136 words == 8 mod 32 -> b128 conflict floor (R6: 0).
// REGISTER DISCIPLINE (the lesson of R4/R5/R7): hard cap = 128 VGPR+AGPR at
// __launch_bounds__(512,4). Budget: bfrag 60 + acc 8 (bands SEQUENTIAL, regs
// reused) + staging <=12 (batches of 3 float4) + temps ~20 => ~100.
// Spill gauge: WRITE_SIZE - 66.6 MB.

typedef __attribute__((ext_vector_type(8))) short bf16x8;
typedef __attribute__((ext_vector_type(4))) float f32x4;

__device__ inline unsigned short f2bf(float f) {   // round-to-nearest-even
    unsigned u = __builtin_bit_cast(unsigned, f);
    u += 0x7FFFu + ((u >> 16) & 1u);
    return (unsigned short)(u >> 16);
}
__device__ inline ushort4 f2bf4(float4 v) {
    ushort4 b; b.x = f2bf(v.x); b.y = f2bf(v.y); b.z = f2bf(v.z); b.w = f2bf(v.w);
    return b;
}

// load one staging item (patch row = base + it/C4R) into v, zero-padded
#define ISSUE_ITEM(base, it, v) {                                         \
    const int _row = (base) + (it) / C4R;                                 \
    const int _c4  = (it) % C4R;                                          \
    const int _gr  = r0 + _row;                                           \
    const int _gc  = c0 + _c4 * 4;                                        \
    if (_row < PR && _gr < N_IN && _gc < N_IN)                            \
        v = *reinterpret_cast<const float4*>(&x[_gr * N_IN + _gc]);       \
}
// convert + write item into its ring slot
#define COMMIT_ITEM(base, it, v) {                                        \
    const int _row = (base) + (it) / C4R;                                 \
    if (_row < PR) {                                                      \
        const int _ring = _row & (RING - 1);                              \
        const int _c4   = (it) % C4R;                                     \
        *reinterpret_cast<ushort4*>(&xs[_ring * PC + _c4 * 4]) = f2bf4(v);\
    }                                                                     \
}

__global__ __launch_bounds__(512, 4) void Conv2DScratch_82025285419642_kernel(
    const float* __restrict__ x, const float* __restrict__ w,
    const float* __restrict__ bias, float* __restrict__ out)
{
    __shared__ unsigned short xs[RING * PC];   // 69,632 B

    const int tid  = threadIdx.x;
    const int lane = tid & 63;
    const int wv   = tid >> 6;            // 0..7 : wave owns cols [32wv, 32wv+32)
    const int m    = lane & 15;           // A row within band / D col
    const int g    = lane >> 4;           // k-group / D row group

    // bijective XCD-chunked block swizzle (512 blocks, 8 XCDs, 64 each)
    const int bid = blockIdx.x;
    const int s   = ((bid & 7) << 6) | (bid >> 3);
    const int c0  = (s & 15) * TN;        // output col base
    const int r0  = (s >> 4) * TM;        // output row base

    // ---- prologue: batch1 in flight while bfrag builds; then batch2 ----
    float4 p0 = make_float4(0.f,0.f,0.f,0.f), p1 = p0, p2 = p0;
    ISSUE_ITEM(0, tid,        p0);
    ISSUE_ITEM(0, tid +  512, p1);
    ISSUE_ITEM(0, tid + 1024, p2);

    // B[(p,q)][n] = w[p][q-n]; lane: n = m, q = g*8+e  (verified R2)
    bf16x8 bfrag[KS];
    #pragma unroll
    for (int p = 0; p < KS; ++p) {
        #pragma unroll
        for (int e = 0; e < 8; ++e) {
            const int idx = g * 8 + e - m;               // filter col
            const float vv = (idx >= 0 && idx < KS) ? w[p * KS + idx] : 0.f;
            bfrag[p][e] = (short)f2bf(vv);
        }
    }
    const float b0 = bias[0];

    COMMIT_ITEM(0, tid,        p0);
    COMMIT_ITEM(0, tid +  512, p1);
    COMMIT_ITEM(0, tid + 1024, p2);

    p0 = make_float4(0.f,0.f,0.f,0.f); p1 = p0; p2 = p0;
    ISSUE_ITEM(0, tid + 1536, p0);
    ISSUE_ITEM(0, tid + 2048, p1);
    ISSUE_ITEM(0, tid + 2560, p2);       // 2560+511 = 3071 < 3128: no guard
    COMMIT_ITEM(0, tid + 1536, p0);
    COMMIT_ITEM(0, tid + 2048, p1);
    COMMIT_ITEM(0, tid + 2560, p2);
    if (tid < PITEMS - 3072) {           // 56-item tail
        float4 pt = make_float4(0.f,0.f,0.f,0.f);
        ISSUE_ITEM(0, tid + 3072, pt);
        COMMIT_ITEM(0, tid + 3072, pt);
    }
    __syncthreads();

    const int colbase = wv * 32 + g * 8;   // A-frag col (bf16) within ring row

    #define STORE_BAND(rbase, a0, a1) {                                   \
        const int _oc  = c0 + wv * 32 + m;                                \
        const int _or0 = r0 + (rbase) + g * 4;                            \
        _Pragma("unroll")                                                 \
        for (int r = 0; r < 4; ++r) {                                     \
            const int _or = _or0 + r;                                     \
            if (_or < N_OUT) {                                            \
                if (_oc < N_OUT)      out[_or * N_OUT + _oc]      = a0[r] + b0; \
                if (_oc + 16 < N_OUT) out[_or * N_OUT + _oc + 16] = a1[r] + b0; \
            }                                                             \
        }                                                                 \
    }

    // ---- ring loop: compute out rows [32c,32c+32), stage patch [32c+46,32c+78) ----
    for (int c = 0; c < NCH; ++c) {
        const int srow = 46 + c * CH;      // staging base row this chunk

        float4 s0 = make_float4(0.f,0.f,0.f,0.f), s1 = s0, s2 = s0;
        ISSUE_ITEM(srow, tid,        s0);
        ISSUE_ITEM(srow, tid +  512, s1);
        ISSUE_ITEM(srow, tid + 1024, s2);

        // band 0 (out rows 32c .. 32c+16)
        f32x4 acc0 = {0.f,0.f,0.f,0.f}, acc1 = acc0;
        {
            const int rb = c * CH + m;
            #pragma unroll
            for (int p = 0; p < KS; ++p) {
                const unsigned short* ap = &xs[((rb + p) & (RING - 1)) * PC + colbase];
                acc0 = __builtin_amdgcn_mfma_f32_16x16x32_bf16(
                    *reinterpret_cast<const bf16x8*>(ap +  0), bfrag[p], acc0, 0, 0, 0);
                acc1 = __builtin_amdgcn_mfma_f32_16x16x32_bf16(
                    *reinterpret_cast<const bf16x8*>(ap + 16), bfrag[p], acc1, 0, 0, 0);
            }
        }
        COMMIT_ITEM(srow, tid,        s0);
        COMMIT_ITEM(srow, tid +  512, s1);
        COMMIT_ITEM(srow, tid + 1024, s2);
        STORE_BAND(c * CH, acc0, acc1);

        s0 = make_float4(0.f,0.f,0.f,0.f); s1 = s0;
        ISSUE_ITEM(srow, tid + 1536, s0);
        if (tid < CITEMS - 2048) ISSUE_ITEM(srow, tid + 2048, s1);   // 128 tail

        // band 1 (out rows 32c+16 .. 32c+32) — acc registers reused
        f32x4 acc2 = {0.f,0.f,0.f,0.f}, acc3 = acc2;
        {
            const int rb = c * CH + 16 + m;
            #pragma unroll
            for (int p = 0; p < KS; ++p) {
                const unsigned short* ap = &xs[((rb + p) & (RING - 1)) * PC + colbase];
                acc2 = __builtin_amdgcn_mfma_f32_16x16x32_bf16(
                    *reinterpret_cast<const bf16x8*>(ap +  0), bfrag[p], acc2, 0, 0, 0);
                acc3 = __builtin_amdgcn_mfma_f32_16x16x32_bf16(
                    *reinterpret_cast<const bf16x8*>(ap + 16), bfrag[p], acc3, 0, 0, 0);
            }
        }
        COMMIT_ITEM(srow, tid + 1536, s0);
        if (tid < CITEMS - 2048) COMMIT_ITEM(srow, tid + 2048, s1);
        STORE_BAND(c * CH + 16, acc2, acc3);

        __syncthreads();                   // staged rows visible for chunk c+1
    }
    #undef STORE_BAND
}

extern "C" void kernel_launch(void* const* d_in, const int* in_sizes, int n_in,
                              void* d_out, int out_size, void* d_ws, size_t ws_size,
                              hipStream_t stream) {
    const float* x    = (const float*)d_in[0];
    const float* w    = (const float*)d_in[1];
    const float* bias = (const float*)d_in[2];
    float* out        = (float*)d_out;

    dim3 block(512);
    dim3 grid(16 * 32);   // 512 blocks, swizzled in-kernel; 2/CU, all resident
    Conv2DScratch_82025285419642_kernel<<<grid, block, 0, stream>>>(x, w, bias, out);
}

// Round 9
// 36.419 us; speedup vs baseline: 2.5452x; 1.5943x over previous
//
#include <hip/hip_runtime.h>

#define N_IN   4096
#define N_OUT  4082      // 4096 - 15 + 1
#define KS     15
#define TM     128       // output rows per block (4 chunks x 32)
#define TN     256       // output cols per block
#define CH     32        // output rows per chunk (2 bands x 16, p-interleaved)
#define NCH    4         // chunks per block
#define PR     142       // patch rows needed (TM + KS - 1)
#define PC     272       // patch cols staged (TN + 16)
#define C4R    68        // float4 chunks per patch row (PC/4)
#define RING   96        // ring rows; per-chunk live span 78 < 96 -> alias-free
#define PITEMS (46 * C4R)          // prologue items (rows [0,46)) = 3128
#define CITEMS (CH * C4R)          // per-chunk staging items = 2176
#define RMOD(r) ((r) >= RING ? (r) - RING : (r))   // rows < 2*RING always

// LDS: ring 96*272*2 = 52,224 B + B-frag table 15*64*16 = 15,360 B = 67,584 B
//   -> 2 blocks/CU at 512 thr.
// REGISTER LESSON (R4/R5/R7/R8): cap = 128 VGPR+AGPR at (512,4); bfrag's 60
// regs never fit -> bfrag now lives in LDS (lane-periodic table, built by
// wave 0). New demand: acc 16 + staging <=12 + B-temp 4 + addr ~25 ~= 60.
// Spill gauge: WRITE_SIZE - 66.6 MB must be ~0.
// Bank: ring pitch 272 bf16 = 136 words == 8 mod 32 -> b128 floor (R6: 0
// conflicts). B-table: lane l -> quad l%8 -> floor as well.

typedef __attribute__((ext_vector_type(8))) short bf16x8;
typedef __attribute__((ext_vector_type(4))) float f32x4;

__device__ inline unsigned short f2bf(float f) {   // round-to-nearest-even
    unsigned u = __builtin_bit_cast(unsigned, f);
    u += 0x7FFFu + ((u >> 16) & 1u);
    return (unsigned short)(u >> 16);
}
__device__ inline ushort4 f2bf4(float4 v) {
    ushort4 b; b.x = f2bf(v.x); b.y = f2bf(v.y); b.z = f2bf(v.z); b.w = f2bf(v.w);
    return b;
}

// load one staging item (patch row = base + it/C4R) into v, zero-padded
#define ISSUE_ITEM(base, it, v) {                                         \
    const int _row = (base) + (it) / C4R;                                 \
    const int _c4  = (it) % C4R;                                          \
    const int _gr  = r0 + _row;                                           \
    const int _gc  = c0 + _c4 * 4;                                        \
    if (_row < PR && _gr < N_IN && _gc < N_IN)                            \
        v = *reinterpret_cast<const float4*>(&x[_gr * N_IN + _gc]);       \
}
// convert + write item into its ring slot
#define COMMIT_ITEM(base, it, v) {                                        \
    const int _row = (base) + (it) / C4R;                                 \
    if (_row < PR) {                                                      \
        const int _ring = RMOD(_row);                                     \
        const int _c4   = (it) % C4R;                                     \
        *reinterpret_cast<ushort4*>(&xs[_ring * PC + _c4 * 4]) = f2bf4(v);\
    }                                                                     \
}

__global__ __launch_bounds__(512, 4) void Conv2DScratch_82025285419642_kernel(
    const float* __restrict__ x, const float* __restrict__ w,
    const float* __restrict__ bias, float* __restrict__ out)
{
    __shared__ unsigned short xs[RING * PC + KS * 64 * 8];   // ring + B table
    unsigned short* bl = &xs[RING * PC];

    const int tid  = threadIdx.x;
    const int lane = tid & 63;
    const int wv   = tid >> 6;            // 0..7 : wave owns cols [32wv, 32wv+32)
    const int m    = lane & 15;           // A row within band / D col
    const int g    = lane >> 4;           // k-group / D row group

    // bijective XCD-chunked block swizzle (512 blocks, 8 XCDs, 64 each)
    const int bid = blockIdx.x;
    const int s   = ((bid & 7) << 6) | (bid >> 3);
    const int c0  = (s & 15) * TN;        // output col base
    const int r0  = (s >> 4) * TM;        // output row base

    // ---- prologue: stage rows [0,46); wave 0 builds B table while in flight ----
    float4 p0 = make_float4(0.f,0.f,0.f,0.f), p1 = p0, p2 = p0;
    ISSUE_ITEM(0, tid,        p0);
    ISSUE_ITEM(0, tid +  512, p1);
    ISSUE_ITEM(0, tid + 1024, p2);

    if (wv == 0) {   // B[(p,q)][n] = w[p][q-n]; lane: n = m, q = g*8+e (verified R2)
        #pragma unroll
        for (int p = 0; p < KS; ++p) {
            bf16x8 f;
            #pragma unroll
            for (int e = 0; e < 8; ++e) {
                const int idx = g * 8 + e - m;           // filter col
                const float vv = (idx >= 0 && idx < KS) ? w[p * KS + idx] : 0.f;
                f[e] = (short)f2bf(vv);
            }
            *reinterpret_cast<bf16x8*>(&bl[(p * 64 + lane) * 8]) = f;
        }
    }
    const float b0 = bias[0];

    COMMIT_ITEM(0, tid,        p0);
    COMMIT_ITEM(0, tid +  512, p1);
    COMMIT_ITEM(0, tid + 1024, p2);

    p0 = make_float4(0.f,0.f,0.f,0.f); p1 = p0; p2 = p0;
    ISSUE_ITEM(0, tid + 1536, p0);
    ISSUE_ITEM(0, tid + 2048, p1);
    ISSUE_ITEM(0, tid + 2560, p2);       // 2560+511 = 3071 < 3128: no guard
    COMMIT_ITEM(0, tid + 1536, p0);
    COMMIT_ITEM(0, tid + 2048, p1);
    COMMIT_ITEM(0, tid + 2560, p2);
    if (tid < PITEMS - 3072) {           // 56-item tail
        float4 pt = make_float4(0.f,0.f,0.f,0.f);
        ISSUE_ITEM(0, tid + 3072, pt);
        COMMIT_ITEM(0, tid + 3072, pt);
    }
    __syncthreads();

    const int colbase = wv * 32 + g * 8;   // A-frag col (bf16) within ring row

    // one p-step: 1 B-read + 4 A-reads + 4 independent MFMAs
    #define PSTEP(p) {                                                    \
        const bf16x8 bf = *reinterpret_cast<const bf16x8*>(               \
            &bl[((p) * 64 + lane) * 8]);                                  \
        const unsigned short* a0p = &xs[RMOD(rb0 + (p)) * PC + colbase];  \
        const unsigned short* a1p = &xs[RMOD(rb1 + (p)) * PC + colbase];  \
        acc00 = __builtin_amdgcn_mfma_f32_16x16x32_bf16(                  \
            *reinterpret_cast<const bf16x8*>(a0p),      bf, acc00, 0,0,0);\
        acc01 = __builtin_amdgcn_mfma_f32_16x16x32_bf16(                  \
            *reinterpret_cast<const bf16x8*>(a0p + 16), bf, acc01, 0,0,0);\
        acc10 = __builtin_amdgcn_mfma_f32_16x16x32_bf16(                  \
            *reinterpret_cast<const bf16x8*>(a1p),      bf, acc10, 0,0,0);\
        acc11 = __builtin_amdgcn_mfma_f32_16x16x32_bf16(                  \
            *reinterpret_cast<const bf16x8*>(a1p + 16), bf, acc11, 0,0,0);\
    }

    #define STORE_BAND(rbase, a0, a1) {                                   \
        const int _oc  = c0 + wv * 32 + m;                                \
        const int _or0 = r0 + (rbase) + g * 4;                            \
        _Pragma("unroll")                                                 \
        for (int r = 0; r < 4; ++r) {                                     \
            const int _or = _or0 + r;                                     \
            if (_or < N_OUT) {                                            \
                if (_oc < N_OUT)      out[_or * N_OUT + _oc]      = a0[r] + b0; \
                if (_oc + 16 < N_OUT) out[_or * N_OUT + _oc + 16] = a1[r] + b0; \
            }                                                             \
        }                                                                 \
    }

    // ---- ring loop: compute out rows [32c,32c+32), stage patch [32c+46,32c+78) ----
    for (int c = 0; c < NCH; ++c) {
        const int srow = 46 + c * CH;      // staging base row this chunk
        const int rb0  = c * CH + m;       // band-0 patch row for p=0
        const int rb1  = rb0 + 16;         // band-1

        float4 s0 = make_float4(0.f,0.f,0.f,0.f), s1 = s0, s2 = s0;
        ISSUE_ITEM(srow, tid,        s0);
        ISSUE_ITEM(srow, tid +  512, s1);
        ISSUE_ITEM(srow, tid + 1024, s2);

        f32x4 acc00 = {0.f,0.f,0.f,0.f}, acc01 = acc00, acc10 = acc00, acc11 = acc00;
        PSTEP(0) PSTEP(1) PSTEP(2) PSTEP(3) PSTEP(4) PSTEP(5) PSTEP(6) PSTEP(7)

        COMMIT_ITEM(srow, tid,        s0);
        COMMIT_ITEM(srow, tid +  512, s1);
        COMMIT_ITEM(srow, tid + 1024, s2);
        s0 = make_float4(0.f,0.f,0.f,0.f); s1 = s0;
        ISSUE_ITEM(srow, tid + 1536, s0);
        if (tid < CITEMS - 2048) ISSUE_ITEM(srow, tid + 2048, s1);   // 128 tail

        PSTEP(8) PSTEP(9) PSTEP(10) PSTEP(11) PSTEP(12) PSTEP(13) PSTEP(14)

        COMMIT_ITEM(srow, tid + 1536, s0);
        if (tid < CITEMS - 2048) COMMIT_ITEM(srow, tid + 2048, s1);

        STORE_BAND(c * CH,      acc00, acc01);
        STORE_BAND(c * CH + 16, acc10, acc11);

        __syncthreads();                   // staged rows visible for chunk c+1
    }
    #undef PSTEP
    #undef STORE_BAND
}

extern "C" void kernel_launch(void* const* d_in, const int* in_sizes, int n_in,
                              void* d_out, int out_size, void* d_ws, size_t ws_size,
                              hipStream_t stream) {
    const float* x    = (const float*)d_in[0];
    const float* w    = (const float*)d_in[1];
    const float* bias = (const float*)d_in[2];
    float* out        = (float*)d_out;

    dim3 block(512);
    dim3 grid(16 * 32);   // 512 blocks, swizzled in-kernel; 2/CU, all resident
    Conv2DScratch_82025285419642_kernel<<<grid, block, 0, stream>>>(x, w, bias, out);
}